// Round 1
// baseline (204.199 us; speedup 1.0000x reference)
//
#include <hip/hip_runtime.h>
#include <math.h>

// Problem constants (B,C,H,W) = (16,64,256,256)
#define CCH 64
#define HWSZ 65536           // 256*256
#define NPIX 1048576         // 16*65536

__global__ __launch_bounds__(256) void softmix_rrelu_kernel(
    const float* __restrict__ x,
    const float* __restrict__ mix,
    const float* __restrict__ bias,
    float* __restrict__ out)
{
    const int p = blockIdx.x * 256 + threadIdx.x;   // pixel id, exact grid
    const int b = p >> 16;                          // / HWSZ
    const int hw = p & (HWSZ - 1);
    const size_t base = (size_t)b * CCH * HWSZ + hw;
    const float* xp = x + base;
    float* op = out + base;

    const float LOG2E = 1.44269504088896340736f;
    const float LN2   = 0.69314718055994530942f;
    const float SLOPE = 0.2f;

    // ---- pass 1: load channels, running max ----
    float e[CCH];
#pragma unroll
    for (int c = 0; c < CCH; ++c)
        e[c] = xp[(size_t)c * HWSZ];          // coalesced across wave

    float m = e[0];
#pragma unroll
    for (int c = 1; c < CCH; ++c)
        m = fmaxf(m, e[c]);

    // ---- exp + sum (keep only e[]; x recovered later via log) ----
    float sum = 0.f;
#pragma unroll
    for (int c = 0; c < CCH; ++c) {
        e[c] = __builtin_exp2f((e[c] - m) * LOG2E);   // v_exp_f32
        sum += e[c];
    }
    const float inv = 1.f / sum;

    // ---- matvec (mix rows are wave-uniform -> s_load), fused epilogue ----
#pragma unroll
    for (int d = 0; d < CCH; ++d) {
        float acc = 0.f;
#pragma unroll
        for (int c = 0; c < CCH; ++c)
            acc = fmaf(mix[d * CCH + c], e[c], acc);  // v_fmac (sgpr src)
        float mixed = acc * inv + bias[d];
        float act = mixed >= 0.f ? mixed : SLOPE * mixed;
        // recover x[d] = m + ln(e[d]);  e[d] = 2^((x-m)*log2e) in (6e-6, 1]
        float xd = fmaf(__builtin_log2f(e[d]), LN2, m);
        float v = fmaf(0.1f, xd, act);
        op[(size_t)d * HWSZ] = v > 0.f ? v : 0.f;
    }
}

extern "C" void kernel_launch(void* const* d_in, const int* in_sizes, int n_in,
                              void* d_out, int out_size, void* d_ws, size_t ws_size,
                              hipStream_t stream) {
    const float* x    = (const float*)d_in[0];
    const float* mix  = (const float*)d_in[1];
    const float* bias = (const float*)d_in[2];
    float* out = (float*)d_out;
    (void)in_sizes; (void)n_in; (void)out_size; (void)d_ws; (void)ws_size;

    dim3 grid(NPIX / 256), block(256);
    softmix_rrelu_kernel<<<grid, block, 0, stream>>>(x, mix, bias, out);
}

// Round 2
// 135.441 us; speedup vs baseline: 1.5077x; 1.5077x over previous
//
#include <hip/hip_runtime.h>
#include <math.h>

// (B,C,H,W) = (16,64,256,256); out[b,d,hw] = relu(rrelu(sum_c mix[d,c]*softmax_c(x)[b,c,hw] + bias[d]) + 0.1*x[b,d,hw])
#define HWSZ 65536

typedef __bf16 bf16x8 __attribute__((ext_vector_type(8)));
typedef float f32x4 __attribute__((ext_vector_type(4)));

__global__ __launch_bounds__(256) void cvt_mix_kernel(const float* __restrict__ mix,
                                                      __bf16* __restrict__ mixb) {
    int i = blockIdx.x * 256 + threadIdx.x;   // 4096 elements total
    mixb[i] = (__bf16)mix[i];
}

__global__ __launch_bounds__(256) void fused_kernel(
    const float* __restrict__ x, const __bf16* __restrict__ mixb,
    const float* __restrict__ bias, float* __restrict__ out)
{
    // per-wave 64x64 bf16 s-tile, [pixel][channel], 16B-granule XOR swizzle
    __shared__ __bf16 sT[4][64 * 64];
    const int tid  = threadIdx.x;
    const int wid  = tid >> 6;
    const int lane = tid & 63;
    const int waveg = blockIdx.x * 4 + wid;       // 16384 waves total
    const int b   = waveg >> 10;                  // 1024 waves per image
    const int hw0 = (waveg & 1023) << 6;          // 64-pixel base
    const size_t ibase = (size_t)b * (64 * HWSZ) + hw0;

    // ---- phase 1: channel softmax for pixel hw0+lane ----
    const float* xp = x + ibase + lane;
    float e[64];
#pragma unroll
    for (int c = 0; c < 64; ++c) e[c] = xp[(size_t)c << 16];   // coalesced

    float m0 = e[0], m1 = e[1], m2 = e[2], m3 = e[3];
#pragma unroll
    for (int c = 4; c < 64; c += 4) {
        m0 = fmaxf(m0, e[c]);     m1 = fmaxf(m1, e[c + 1]);
        m2 = fmaxf(m2, e[c + 2]); m3 = fmaxf(m3, e[c + 3]);
    }
    const float m = fmaxf(fmaxf(m0, m1), fmaxf(m2, m3));

    const float LOG2E = 1.44269504088896340736f;
    float s0 = 0.f, s1 = 0.f, s2 = 0.f, s3 = 0.f;
#pragma unroll
    for (int c = 0; c < 64; c += 4) {
        e[c]     = __builtin_exp2f((e[c]     - m) * LOG2E); s0 += e[c];
        e[c + 1] = __builtin_exp2f((e[c + 1] - m) * LOG2E); s1 += e[c + 1];
        e[c + 2] = __builtin_exp2f((e[c + 2] - m) * LOG2E); s2 += e[c + 2];
        e[c + 3] = __builtin_exp2f((e[c + 3] - m) * LOG2E); s3 += e[c + 3];
    }
    const float inv = 1.f / ((s0 + s1) + (s2 + s3));

    // write s (= e*inv) as bf16 row [lane][0..63], swizzled 16B granules
    __bf16* my = &sT[wid][0];
#pragma unroll
    for (int j = 0; j < 8; ++j) {
        bf16x8 v;
#pragma unroll
        for (int i = 0; i < 8; ++i) v[i] = (__bf16)(e[j * 8 + i] * inv);
        const int gr = j ^ (lane & 7);
        *reinterpret_cast<bf16x8*>(my + lane * 64 + gr * 8) = v;
    }
    __syncthreads();

    // ---- phase 2: D[d][p] = sum_c mix[d][c] * s[c][p] via MFMA ----
    f32x4 acc[4][4] = {};
    const int l15 = lane & 15, lhi = lane >> 4;
#pragma unroll
    for (int kt = 0; kt < 2; ++kt) {
        bf16x8 A[4], B[4];
        // A fragment: lane holds row m=l15, k = kt*32 + lhi*8 + 0..7 (contiguous)
        const __bf16* ab = mixb + l15 * 64 + kt * 32 + lhi * 8;
#pragma unroll
        for (int mt = 0; mt < 4; ++mt)
            A[mt] = *reinterpret_cast<const bf16x8*>(ab + mt * 16 * 64);
        // B fragment: lane holds col n=l15 (pixel), same contiguous k slice
#pragma unroll
        for (int nt = 0; nt < 4; ++nt) {
            const int row = nt * 16 + l15;
            const int g = (kt * 4 + lhi) ^ (row & 7);
            B[nt] = *reinterpret_cast<const bf16x8*>(my + row * 64 + g * 8);
        }
#pragma unroll
        for (int mt = 0; mt < 4; ++mt)
#pragma unroll
            for (int nt = 0; nt < 4; ++nt)
                acc[mt][nt] = __builtin_amdgcn_mfma_f32_16x16x32_bf16(
                    A[mt], B[nt], acc[mt][nt], 0, 0, 0);
    }

    // ---- phase 3: bias + RReLU + 0.1*x + ReLU, coalesced stores ----
    // C/D map: row (d within tile) = lhi*4 + reg, col (pixel) = l15
#pragma unroll
    for (int mt = 0; mt < 4; ++mt) {
#pragma unroll
        for (int r = 0; r < 4; ++r) {
            const int d = mt * 16 + lhi * 4 + r;
            const float bd = bias[d];
            const float* xr  = x   + ibase + (size_t)d * HWSZ;
            float*       orw = out + ibase + (size_t)d * HWSZ;
#pragma unroll
            for (int nt = 0; nt < 4; ++nt) {
                const int p = nt * 16 + l15;
                float mixed = acc[mt][nt][r] + bd;
                float act = mixed >= 0.f ? mixed : 0.2f * mixed;
                float v = fmaf(0.1f, xr[p], act);   // x re-read is L1/L2-hot
                orw[p] = fmaxf(v, 0.f);
            }
        }
    }
}

extern "C" void kernel_launch(void* const* d_in, const int* in_sizes, int n_in,
                              void* d_out, int out_size, void* d_ws, size_t ws_size,
                              hipStream_t stream) {
    const float* x    = (const float*)d_in[0];
    const float* mix  = (const float*)d_in[1];
    const float* bias = (const float*)d_in[2];
    float* out = (float*)d_out;
    __bf16* mixb = (__bf16*)d_ws;    // 4096 * 2B
    (void)in_sizes; (void)n_in; (void)out_size; (void)ws_size;

    cvt_mix_kernel<<<dim3(16), dim3(256), 0, stream>>>(mix, mixb);
    fused_kernel<<<dim3(4096), dim3(256), 0, stream>>>(x, mixb, bias, out);
}

// Round 3
// 121.269 us; speedup vs baseline: 1.6839x; 1.1169x over previous
//
#include <hip/hip_runtime.h>
#include <math.h>

// (B,C,H,W) = (16,64,256,256)
// out[b,d,hw] = relu( rrelu( sum_c mix[d,c]*softmax_c(x)[b,c,hw] + bias[d] ) + 0.1*x[b,d,hw] )
#define HWSZ 65536

typedef __bf16 bf16x8 __attribute__((ext_vector_type(8)));
typedef __bf16 bf16x4 __attribute__((ext_vector_type(4)));
typedef float f32x4 __attribute__((ext_vector_type(4)));

__global__ __launch_bounds__(256) void cvt_mix_kernel(const float* __restrict__ mix,
                                                      __bf16* __restrict__ mixb) {
    int i = blockIdx.x * 256 + threadIdx.x;   // 4096 elements
    mixb[i] = (__bf16)mix[i];
}

__global__ __launch_bounds__(256) void fused_kernel(
    const float* __restrict__ x, const __bf16* __restrict__ mixb,
    const float* __restrict__ bias, float* __restrict__ out)
{
    // per-wave 64x64 bf16 s-tile, [pixel][channel], 16B-granule XOR swizzle.
    // Waves never touch each other's slice -> no __syncthreads anywhere.
    __shared__ __bf16 sT[4][64 * 64];
    const int tid  = threadIdx.x;
    const int wid  = tid >> 6;
    const int lane = tid & 63;
    const int waveg = blockIdx.x * 4 + wid;       // 16384 waves
    const int b   = waveg >> 10;
    const int hw0 = (waveg & 1023) << 6;
    const size_t ibase = (size_t)b * (64 * HWSZ) + hw0;

    const float LOG2E = 1.44269504088896340736f;
    const float LN2   = 0.69314718055994530942f;

    // ---- phase 1: channel softmax for pixel hw0+lane ----
    const float* xp = x + ibase + lane;
    float e[64];
#pragma unroll
    for (int c = 0; c < 64; ++c) e[c] = xp[(size_t)c << 16];   // coalesced 256B/instr

    float m0 = e[0], m1 = e[1], m2 = e[2], m3 = e[3];
#pragma unroll
    for (int c = 4; c < 64; c += 4) {
        m0 = fmaxf(m0, e[c]);     m1 = fmaxf(m1, e[c + 1]);
        m2 = fmaxf(m2, e[c + 2]); m3 = fmaxf(m3, e[c + 3]);
    }
    const float m = fmaxf(fmaxf(m0, m1), fmaxf(m2, m3));

    float s0 = 0.f, s1 = 0.f, s2 = 0.f, s3 = 0.f;
#pragma unroll
    for (int c = 0; c < 64; c += 4) {
        e[c]     = __builtin_exp2f((e[c]     - m) * LOG2E); s0 += e[c];
        e[c + 1] = __builtin_exp2f((e[c + 1] - m) * LOG2E); s1 += e[c + 1];
        e[c + 2] = __builtin_exp2f((e[c + 2] - m) * LOG2E); s2 += e[c + 2];
        e[c + 3] = __builtin_exp2f((e[c + 3] - m) * LOG2E); s3 += e[c + 3];
    }
    const float sum = (s0 + s1) + (s2 + s3);
    const float inv = 1.f / sum;
    // per-pixel constant for x-recovery: x[c] = ln(s[c]) + M,  M = m + ln(sum)
    const float Mv = fmaf(LN2, __builtin_log2f(sum), m);

    // write s = e*inv as bf16 row [lane][c], swizzled 16B granules
    __bf16* my = &sT[wid][0];
#pragma unroll
    for (int j = 0; j < 8; ++j) {
        bf16x8 v;
#pragma unroll
        for (int i = 0; i < 8; ++i) v[i] = (__bf16)(e[j * 8 + i] * inv);
        const int gr = j ^ (lane & 7);
        *reinterpret_cast<bf16x8*>(my + lane * 64 + gr * 8) = v;
    }
    // wave-local LDS visibility (lockstep lanes); no cross-wave sharing
    asm volatile("s_waitcnt lgkmcnt(0)" ::: "memory");

    // ---- phase 2: D[d][p] = sum_c mix[d][c] * s[c][p] via MFMA ----
    f32x4 acc[4][4] = {};
    const int l15 = lane & 15, lhi = lane >> 4;
#pragma unroll
    for (int kt = 0; kt < 2; ++kt) {
        bf16x8 A[4], B[4];
        const __bf16* ab = mixb + l15 * 64 + kt * 32 + lhi * 8;
#pragma unroll
        for (int mt = 0; mt < 4; ++mt)
            A[mt] = *reinterpret_cast<const bf16x8*>(ab + mt * 16 * 64);
#pragma unroll
        for (int nt = 0; nt < 4; ++nt) {
            const int row = nt * 16 + l15;            // pixel
            const int g = (kt * 4 + lhi) ^ (row & 7);
            B[nt] = *reinterpret_cast<const bf16x8*>(my + row * 64 + g * 8);
        }
#pragma unroll
        for (int mt = 0; mt < 4; ++mt)
#pragma unroll
            for (int nt = 0; nt < 4; ++nt)
                acc[mt][nt] = __builtin_amdgcn_mfma_f32_16x16x32_bf16(
                    A[mt], B[nt], acc[mt][nt], 0, 0, 0);
    }

    // M[p] for the 4 pixels this lane's epilogue touches (held by lane p)
    float Mp[4];
#pragma unroll
    for (int nt = 0; nt < 4; ++nt)
        Mp[nt] = __shfl(Mv, nt * 16 + l15, 64);

    // ---- phase 3: bias + RReLU + 0.1*x + ReLU; x recovered from LDS s ----
    // C/D map: row(d within tile) = lhi*4 + r, col(pixel) = l15
#pragma unroll
    for (int mt = 0; mt < 4; ++mt) {
        const int d0 = mt * 16 + lhi * 4;
        const float b0 = bias[d0], b1 = bias[d0 + 1], b2 = bias[d0 + 2], b3 = bias[d0 + 3];
        const float bb[4] = {b0, b1, b2, b3};
#pragma unroll
        for (int nt = 0; nt < 4; ++nt) {
            const int p = nt * 16 + l15;
            // s[p][d0..d0+3]: granule (d0>>3)^(p&7), start (d0&7) -> 8B aligned
            const int g = ((d0 >> 3) ^ (p & 7));
            const bf16x4 sv = *reinterpret_cast<const bf16x4*>(
                my + p * 64 + g * 8 + (d0 & 7));
            float* orw = out + ibase + (size_t)d0 * HWSZ + p;
#pragma unroll
            for (int r = 0; r < 4; ++r) {
                float mixed = acc[mt][nt][r] + bb[r];
                float act = fmaxf(mixed, 0.2f * mixed);          // RReLU (slope>0)
                float xv = fmaf(LN2, __builtin_log2f((float)sv[r]), Mp[nt]);
                float v = fmaf(0.1f, xv, act);
                orw[(size_t)r * HWSZ] = fmaxf(v, 0.f);
            }
        }
    }
}

extern "C" void kernel_launch(void* const* d_in, const int* in_sizes, int n_in,
                              void* d_out, int out_size, void* d_ws, size_t ws_size,
                              hipStream_t stream) {
    const float* x    = (const float*)d_in[0];
    const float* mix  = (const float*)d_in[1];
    const float* bias = (const float*)d_in[2];
    float* out = (float*)d_out;
    __bf16* mixb = (__bf16*)d_ws;    // 4096 * 2B
    (void)in_sizes; (void)n_in; (void)out_size; (void)ws_size;

    cvt_mix_kernel<<<dim3(16), dim3(256), 0, stream>>>(mix, mixb);
    fused_kernel<<<dim3(4096), dim3(256), 0, stream>>>(x, mixb, bias, out);
}

// Round 4
// 119.663 us; speedup vs baseline: 1.7065x; 1.0134x over previous
//
#include <hip/hip_runtime.h>
#include <math.h>

// (B,C,H,W) = (16,64,256,256)
// out[b,d,hw] = relu( rrelu( sum_c mix[d,c]*softmax_c(x)[b,c,hw] + bias[d] ) + 0.1*x[b,d,hw] )
#define HWSZ 65536

typedef __bf16 bf16x8 __attribute__((ext_vector_type(8)));
typedef __bf16 bf16x4 __attribute__((ext_vector_type(4)));
typedef float f32x4 __attribute__((ext_vector_type(4)));

__global__ __launch_bounds__(256) void cvt_mix_kernel(const float* __restrict__ mix,
                                                      __bf16* __restrict__ mixb) {
    int i = blockIdx.x * 256 + threadIdx.x;   // 4096 elements
    mixb[i] = (__bf16)mix[i];
}

__global__ __launch_bounds__(256, 5) void fused_kernel(
    const float* __restrict__ x, const __bf16* __restrict__ mixb,
    const float* __restrict__ bias, float* __restrict__ out)
{
    // per-wave 64x64 bf16 s-tile, [pixel][channel], 16B-granule XOR swizzle.
    // Waves never touch each other's slice -> no __syncthreads anywhere.
    __shared__ __bf16 sT[4][64 * 64];
    const int tid  = threadIdx.x;
    const int wid  = tid >> 6;
    const int lane = tid & 63;
    const int waveg = blockIdx.x * 4 + wid;       // 16384 waves
    const int b   = waveg >> 10;
    const int hw0 = (waveg & 1023) << 6;
    const size_t ibase = (size_t)b * (64 * HWSZ) + hw0;

    const float LOG2E = 1.44269504088896340736f;
    const float LN2   = 0.69314718055994530942f;

    // ---- phase 1: channel softmax for pixel hw0+lane ----
    const float* xp = x + ibase + lane;
    float e[64];
#pragma unroll
    for (int c = 0; c < 64; ++c) e[c] = xp[(size_t)c << 16];   // coalesced 256B/instr

    float m0 = e[0], m1 = e[1], m2 = e[2], m3 = e[3];
#pragma unroll
    for (int c = 4; c < 64; c += 4) {
        m0 = fmaxf(m0, e[c]);     m1 = fmaxf(m1, e[c + 1]);
        m2 = fmaxf(m2, e[c + 2]); m3 = fmaxf(m3, e[c + 3]);
    }
    const float m = fmaxf(fmaxf(m0, m1), fmaxf(m2, m3));

    float s0 = 0.f, s1 = 0.f, s2 = 0.f, s3 = 0.f;
#pragma unroll
    for (int c = 0; c < 64; c += 4) {
        e[c]     = __builtin_exp2f((e[c]     - m) * LOG2E); s0 += e[c];
        e[c + 1] = __builtin_exp2f((e[c + 1] - m) * LOG2E); s1 += e[c + 1];
        e[c + 2] = __builtin_exp2f((e[c + 2] - m) * LOG2E); s2 += e[c + 2];
        e[c + 3] = __builtin_exp2f((e[c + 3] - m) * LOG2E); s3 += e[c + 3];
    }
    const float sum = (s0 + s1) + (s2 + s3);
    const float inv = 1.f / sum;
    // per-pixel constant for x-recovery: x[c] = ln(s[c]) + M,  M = m + ln(sum)
    const float Mv = fmaf(LN2, __builtin_log2f(sum), m);

    // write s = e*inv as bf16 row [lane][c], swizzled 16B granules
    __bf16* my = &sT[wid][0];
#pragma unroll
    for (int j = 0; j < 8; ++j) {
        bf16x8 v;
#pragma unroll
        for (int i = 0; i < 8; ++i) v[i] = (__bf16)(e[j * 8 + i] * inv);
        const int gr = j ^ (lane & 7);
        *reinterpret_cast<bf16x8*>(my + lane * 64 + gr * 8) = v;
    }
    // wave-local LDS visibility (lockstep lanes); no cross-wave sharing
    asm volatile("s_waitcnt lgkmcnt(0)" ::: "memory");

    const int l15 = lane & 15, lhi = lane >> 4;

    // M[p] for the 4 pixels this lane's epilogue touches (held by lane p)
    float Mp[4];
#pragma unroll
    for (int nt = 0; nt < 4; ++nt)
        Mp[nt] = __shfl(Mv, nt * 16 + l15, 64);

    // ---- phases 2+3 in two d-halves: acc[2][4] keeps VGPR pressure low ----
#pragma unroll
    for (int mtp = 0; mtp < 2; ++mtp) {
        f32x4 acc[2][4] = {};
#pragma unroll
        for (int kt = 0; kt < 2; ++kt) {
            bf16x8 A[2], B[4];
            const __bf16* ab = mixb + (mtp * 32 + l15) * 64 + kt * 32 + lhi * 8;
#pragma unroll
            for (int mt = 0; mt < 2; ++mt)
                A[mt] = *reinterpret_cast<const bf16x8*>(ab + mt * 16 * 64);
#pragma unroll
            for (int nt = 0; nt < 4; ++nt) {
                const int row = nt * 16 + l15;            // pixel
                const int g = (kt * 4 + lhi) ^ (row & 7);
                B[nt] = *reinterpret_cast<const bf16x8*>(my + row * 64 + g * 8);
            }
#pragma unroll
            for (int mt = 0; mt < 2; ++mt)
#pragma unroll
                for (int nt = 0; nt < 4; ++nt)
                    acc[mt][nt] = __builtin_amdgcn_mfma_f32_16x16x32_bf16(
                        A[mt], B[nt], acc[mt][nt], 0, 0, 0);
        }

        // epilogue for d in [mtp*32, mtp*32+32); stores are fire-and-forget
#pragma unroll
        for (int mt = 0; mt < 2; ++mt) {
            const int d0 = mtp * 32 + mt * 16 + lhi * 4;
            const float bb[4] = {bias[d0], bias[d0 + 1], bias[d0 + 2], bias[d0 + 3]};
#pragma unroll
            for (int nt = 0; nt < 4; ++nt) {
                const int p = nt * 16 + l15;
                // s[p][d0..d0+3]: granule (d0>>3)^(p&7), 8B-aligned start
                const int g = ((d0 >> 3) ^ (p & 7));
                const bf16x4 sv = *reinterpret_cast<const bf16x4*>(
                    my + p * 64 + g * 8 + (d0 & 7));
                float* orw = out + ibase + (size_t)d0 * HWSZ + p;
#pragma unroll
                for (int r = 0; r < 4; ++r) {
                    float mixed = acc[mt][nt][r] + bb[r];
                    float act = fmaxf(mixed, 0.2f * mixed);      // RReLU (slope>0)
                    float xv = fmaf(LN2, __builtin_log2f((float)sv[r]), Mp[nt]);
                    float v = fmaf(0.1f, xv, act);
                    orw[(size_t)r * HWSZ] = fmaxf(v, 0.f);
                }
            }
        }
    }
}

extern "C" void kernel_launch(void* const* d_in, const int* in_sizes, int n_in,
                              void* d_out, int out_size, void* d_ws, size_t ws_size,
                              hipStream_t stream) {
    const float* x    = (const float*)d_in[0];
    const float* mix  = (const float*)d_in[1];
    const float* bias = (const float*)d_in[2];
    float* out = (float*)d_out;
    __bf16* mixb = (__bf16*)d_ws;    // 4096 * 2B
    (void)in_sizes; (void)n_in; (void)out_size; (void)ws_size;

    cvt_mix_kernel<<<dim3(16), dim3(256), 0, stream>>>(mix, mixb);
    fused_kernel<<<dim3(4096), dim3(256), 0, stream>>>(x, mixb, bias, out);
}